// Round 3
// baseline (237.400 us; speedup 1.0000x reference)
//
#include <hip/hip_runtime.h>
#include <math.h>

// Sparsemax, split into two pure HBM streams:
//   1. hipMemsetAsync zeros d_out (write-only stream, ~6.9 TB/s).
//   2. Read-only kernel streams X, computes rowmax + the candidate set
//      {x > rowmax-1} (tau can only increase from tau0 = rowmax-1, so all
//      final nonzeros are candidates), runs single-wave Newton on the tiny
//      LDS candidate set, and scatter-writes only the ~6 nonzero outputs
//      per row. The 512 MB of zeros never flows through the kernel.
// Fallback (candidate overflow, never taken for Gaussian rows): block-wide
// Newton over registers + full row write.

constexpr int D       = 32000;
constexpr int NV4     = D / 4;          // 8000 float4 per row
constexpr int THREADS = 1024;
constexpr int NWAVES  = THREADS / 64;   // 16 waves
constexpr int VPT     = 8;              // float4 per thread: 8*1024 = 8192 >= 8000
constexpr int CAP     = 2048;           // candidate capacity (16 KB LDS)

__global__ __launch_bounds__(THREADS, 8)
void sparsemax_tau_scatter(const float* __restrict__ X, float* __restrict__ Y) {
    const int row  = blockIdx.x;
    const int tid  = threadIdx.x;
    const int wid  = tid >> 6;
    const int lane = tid & 63;

    const float4* xr = reinterpret_cast<const float4*>(X + (size_t)row * D);

    __shared__ float sa[NWAVES];
    __shared__ float cval[CAP];
    __shared__ int   cidx[CAP];
    __shared__ int   cnt;

    if (tid == 0) cnt = 0;

    // ---- load the whole row into registers (coalesced, 16B/lane) ----
    float4 r[VPT];
    #pragma unroll
    for (int j = 0; j < VPT; ++j) {
        const int idx = tid + j * THREADS;
        if (idx < NV4) {
            r[j] = xr[idx];
        } else {
            r[j] = make_float4(-INFINITY, -INFINITY, -INFINITY, -INFINITY);
        }
    }

    // ---- row max ----
    float m = -INFINITY;
    #pragma unroll
    for (int j = 0; j < VPT; ++j)
        m = fmaxf(m, fmaxf(fmaxf(r[j].x, r[j].y), fmaxf(r[j].z, r[j].w)));
    #pragma unroll
    for (int off = 32; off >= 1; off >>= 1)
        m = fmaxf(m, __shfl_xor(m, off, 64));
    if (lane == 0) sa[wid] = m;
    __syncthreads();                       // also orders cnt=0 vs atomics below
    float rowmax = sa[0];
    #pragma unroll
    for (int w = 1; w < NWAVES; ++w) rowmax = fmaxf(rowmax, sa[w]);

    // ---- collect candidates (value, index) with x > rowmax - 1 ----
    const float thresh = rowmax - 1.0f;
    #pragma unroll
    for (int j = 0; j < VPT; ++j) {
        const int base = (tid + j * THREADS) * 4;
        float v;
        v = r[j].x; if (v > thresh) { int i = atomicAdd(&cnt, 1); if (i < CAP) { cval[i] = v; cidx[i] = base + 0; } }
        v = r[j].y; if (v > thresh) { int i = atomicAdd(&cnt, 1); if (i < CAP) { cval[i] = v; cidx[i] = base + 1; } }
        v = r[j].z; if (v > thresh) { int i = atomicAdd(&cnt, 1); if (i < CAP) { cval[i] = v; cidx[i] = base + 2; } }
        v = r[j].w; if (v > thresh) { int i = atomicAdd(&cnt, 1); if (i < CAP) { cval[i] = v; cidx[i] = base + 3; } }
    }
    __syncthreads();
    const int K = cnt;

    if (K <= CAP) {
        // ---- single-wave Newton + scatter of the <=K nonzeros ----
        if (wid == 0) {
            float t = thresh;
            for (int it = 0; it < 60; ++it) {
                float s = 0.0f, c = 0.0f;
                for (int i = lane; i < K; i += 64) {
                    const float v = cval[i] - t;
                    if (v > 0.0f) { s += v; c += 1.0f; }
                }
                #pragma unroll
                for (int off = 32; off >= 1; off >>= 1) {
                    s += __shfl_xor(s, off, 64);
                    c += __shfl_xor(c, off, 64);
                }
                const float f = s - 1.0f;
                if (f <= 1e-6f) break;
                const float nt = t + f / c;   // c >= 1 (rowmax is always active)
                if (nt == t) break;
                t = nt;
            }
            float s = 0.0f;
            for (int i = lane; i < K; i += 64) s += fmaxf(cval[i] - t, 0.0f);
            #pragma unroll
            for (int off = 32; off >= 1; off >>= 1) s += __shfl_xor(s, off, 64);
            const float inv = 1.0f / s;
            float* yrow = Y + (size_t)row * D;
            for (int i = lane; i < K; i += 64)
                yrow[cidx[i]] = fmaxf(cval[i] - t, 0.0f) * inv;
        }
        // other waves: done (zeros already written by memset)
    } else {
        // ---- fallback: block-wide Newton over registers + full row write ----
        __shared__ float fa[NWAVES], fb[NWAVES];
        float tau = thresh;
        for (int it = 0; it < 60; ++it) {
            float s = 0.0f, c = 0.0f;
            #pragma unroll
            for (int j = 0; j < VPT; ++j) {
                float v;
                v = r[j].x - tau; if (v > 0.0f) { s += v; c += 1.0f; }
                v = r[j].y - tau; if (v > 0.0f) { s += v; c += 1.0f; }
                v = r[j].z - tau; if (v > 0.0f) { s += v; c += 1.0f; }
                v = r[j].w - tau; if (v > 0.0f) { s += v; c += 1.0f; }
            }
            #pragma unroll
            for (int off = 32; off >= 1; off >>= 1) {
                s += __shfl_xor(s, off, 64);
                c += __shfl_xor(c, off, 64);
            }
            __syncthreads();
            if (lane == 0) { fa[wid] = s; fb[wid] = c; }
            __syncthreads();
            float S = 0.0f, C = 0.0f;
            #pragma unroll
            for (int w = 0; w < NWAVES; ++w) { S += fa[w]; C += fb[w]; }
            const float f = S - 1.0f;
            if (f <= 1e-6f) break;
            const float nt = tau + f / C;
            if (nt == tau) break;
            tau = nt;
        }
        float s = 0.0f;
        #pragma unroll
        for (int j = 0; j < VPT; ++j) {
            s += fmaxf(r[j].x - tau, 0.0f);
            s += fmaxf(r[j].y - tau, 0.0f);
            s += fmaxf(r[j].z - tau, 0.0f);
            s += fmaxf(r[j].w - tau, 0.0f);
        }
        #pragma unroll
        for (int off = 32; off >= 1; off >>= 1) s += __shfl_xor(s, off, 64);
        __syncthreads();
        if (lane == 0) fa[wid] = s;
        __syncthreads();
        float S = 0.0f;
        #pragma unroll
        for (int w = 0; w < NWAVES; ++w) S += fa[w];
        const float inv = 1.0f / S;

        float4* yr = reinterpret_cast<float4*>(Y + (size_t)row * D);
        #pragma unroll
        for (int j = 0; j < VPT; ++j) {
            const int idx = tid + j * THREADS;
            if (idx < NV4) {
                float4 o;
                o.x = fmaxf(r[j].x - tau, 0.0f) * inv;
                o.y = fmaxf(r[j].y - tau, 0.0f) * inv;
                o.z = fmaxf(r[j].z - tau, 0.0f) * inv;
                o.w = fmaxf(r[j].w - tau, 0.0f) * inv;
                yr[idx] = o;
            }
        }
    }
}

extern "C" void kernel_launch(void* const* d_in, const int* in_sizes, int n_in,
                              void* d_out, int out_size, void* d_ws, size_t ws_size,
                              hipStream_t stream) {
    const float* X = (const float*)d_in[0];
    float*       Y = (float*)d_out;
    const int rows = in_sizes[0] / D;
    hipMemsetAsync(d_out, 0, (size_t)out_size * sizeof(float), stream);
    sparsemax_tau_scatter<<<rows, THREADS, 0, stream>>>(X, Y);
}

// Round 4
// 224.971 us; speedup vs baseline: 1.0552x; 1.0552x over previous
//
#include <hip/hip_runtime.h>
#include <math.h>

// Sparsemax fused single-pass:
//   - Each block owns one row. The load loop interleaves { load x, store 0 }
//     so both HBM directions are in flight from the start (copy-like pattern);
//     the zeros (all of the output except ~6 elements/row) don't depend on tau.
//   - rowmax + candidate set {x > rowmax-1} (tau only increases from
//     tau0 = rowmax-1, so all final nonzeros are candidates).
//   - Single-wave Newton on the tiny LDS candidate set, then scatter-write of
//     the <=K nonzeros (ordered after the zero stores by __syncthreads'
//     vmcnt drain).
// Fallback (candidate overflow; never taken for Gaussian rows): block-wide
// Newton over registers + full row overwrite.

constexpr int D       = 32000;
constexpr int NV4     = D / 4;          // 8000 float4 per row
constexpr int THREADS = 1024;
constexpr int NWAVES  = THREADS / 64;   // 16 waves
constexpr int VPT     = 8;              // float4 per thread: 8*1024 = 8192 >= 8000
constexpr int CAP     = 2048;           // candidate capacity

__global__ __launch_bounds__(THREADS, 8)
void sparsemax_fused(const float* __restrict__ X, float* __restrict__ Y) {
    const int row  = blockIdx.x;
    const int tid  = threadIdx.x;
    const int wid  = tid >> 6;
    const int lane = tid & 63;

    const float4* xr = reinterpret_cast<const float4*>(X + (size_t)row * D);
    float4*       yr = reinterpret_cast<float4*>(Y + (size_t)row * D);

    __shared__ float sa[NWAVES];
    __shared__ float cval[CAP];
    __shared__ int   cidx[CAP];
    __shared__ int   cnt;

    if (tid == 0) cnt = 0;

    // ---- interleaved: load row into registers + stream zeros to output ----
    const float4 zero4 = make_float4(0.0f, 0.0f, 0.0f, 0.0f);
    float4 r[VPT];
    #pragma unroll
    for (int j = 0; j < VPT; ++j) {
        const int idx = tid + j * THREADS;
        if (idx < NV4) {
            r[j] = xr[idx];
            yr[idx] = zero4;            // independent of the load; both streams fly
        } else {
            r[j] = make_float4(-INFINITY, -INFINITY, -INFINITY, -INFINITY);
        }
    }

    // ---- row max ----
    float m = -INFINITY;
    #pragma unroll
    for (int j = 0; j < VPT; ++j)
        m = fmaxf(m, fmaxf(fmaxf(r[j].x, r[j].y), fmaxf(r[j].z, r[j].w)));
    #pragma unroll
    for (int off = 32; off >= 1; off >>= 1)
        m = fmaxf(m, __shfl_xor(m, off, 64));
    if (lane == 0) sa[wid] = m;
    __syncthreads();                     // also orders cnt=0 vs atomics below
    float rowmax = sa[0];
    #pragma unroll
    for (int w = 1; w < NWAVES; ++w) rowmax = fmaxf(rowmax, sa[w]);

    // ---- collect candidates (value, index) with x > rowmax - 1 ----
    const float thresh = rowmax - 1.0f;
    #pragma unroll
    for (int j = 0; j < VPT; ++j) {
        const int base = (tid + j * THREADS) * 4;
        float v;
        v = r[j].x; if (v > thresh) { int i = atomicAdd(&cnt, 1); if (i < CAP) { cval[i] = v; cidx[i] = base + 0; } }
        v = r[j].y; if (v > thresh) { int i = atomicAdd(&cnt, 1); if (i < CAP) { cval[i] = v; cidx[i] = base + 1; } }
        v = r[j].z; if (v > thresh) { int i = atomicAdd(&cnt, 1); if (i < CAP) { cval[i] = v; cidx[i] = base + 2; } }
        v = r[j].w; if (v > thresh) { int i = atomicAdd(&cnt, 1); if (i < CAP) { cval[i] = v; cidx[i] = base + 3; } }
    }
    __syncthreads();                     // drains vmcnt: zero stores complete
    const int K = cnt;

    if (K <= CAP) {
        // ---- single-wave Newton + scatter of the <=K nonzeros ----
        if (wid == 0) {
            float t = thresh;
            for (int it = 0; it < 60; ++it) {
                float s = 0.0f, c = 0.0f;
                for (int i = lane; i < K; i += 64) {
                    const float v = cval[i] - t;
                    if (v > 0.0f) { s += v; c += 1.0f; }
                }
                #pragma unroll
                for (int off = 32; off >= 1; off >>= 1) {
                    s += __shfl_xor(s, off, 64);
                    c += __shfl_xor(c, off, 64);
                }
                const float f = s - 1.0f;
                if (f <= 1e-6f) break;
                const float nt = t + f / c;   // c >= 1 (rowmax is always active)
                if (nt == t) break;
                t = nt;
            }
            float s = 0.0f;
            for (int i = lane; i < K; i += 64) s += fmaxf(cval[i] - t, 0.0f);
            #pragma unroll
            for (int off = 32; off >= 1; off >>= 1) s += __shfl_xor(s, off, 64);
            const float inv = 1.0f / s;
            float* yrow = Y + (size_t)row * D;
            for (int i = lane; i < K; i += 64)
                yrow[cidx[i]] = fmaxf(cval[i] - t, 0.0f) * inv;
        }
        // other waves: done (zeros already written above)
    } else {
        // ---- fallback: block-wide Newton over registers + full row write ----
        __shared__ float fa[NWAVES], fb[NWAVES];
        float tau = thresh;
        for (int it = 0; it < 60; ++it) {
            float s = 0.0f, c = 0.0f;
            #pragma unroll
            for (int j = 0; j < VPT; ++j) {
                float v;
                v = r[j].x - tau; if (v > 0.0f) { s += v; c += 1.0f; }
                v = r[j].y - tau; if (v > 0.0f) { s += v; c += 1.0f; }
                v = r[j].z - tau; if (v > 0.0f) { s += v; c += 1.0f; }
                v = r[j].w - tau; if (v > 0.0f) { s += v; c += 1.0f; }
            }
            #pragma unroll
            for (int off = 32; off >= 1; off >>= 1) {
                s += __shfl_xor(s, off, 64);
                c += __shfl_xor(c, off, 64);
            }
            __syncthreads();
            if (lane == 0) { fa[wid] = s; fb[wid] = c; }
            __syncthreads();
            float S = 0.0f, C = 0.0f;
            #pragma unroll
            for (int w = 0; w < NWAVES; ++w) { S += fa[w]; C += fb[w]; }
            const float f = S - 1.0f;
            if (f <= 1e-6f) break;
            const float nt = tau + f / C;
            if (nt == tau) break;
            tau = nt;
        }
        float s = 0.0f;
        #pragma unroll
        for (int j = 0; j < VPT; ++j) {
            s += fmaxf(r[j].x - tau, 0.0f);
            s += fmaxf(r[j].y - tau, 0.0f);
            s += fmaxf(r[j].z - tau, 0.0f);
            s += fmaxf(r[j].w - tau, 0.0f);
        }
        #pragma unroll
        for (int off = 32; off >= 1; off >>= 1) s += __shfl_xor(s, off, 64);
        __syncthreads();
        if (lane == 0) fa[wid] = s;
        __syncthreads();
        float S = 0.0f;
        #pragma unroll
        for (int w = 0; w < NWAVES; ++w) S += fa[w];
        const float inv = 1.0f / S;

        #pragma unroll
        for (int j = 0; j < VPT; ++j) {
            const int idx = tid + j * THREADS;
            if (idx < NV4) {
                float4 o;
                o.x = fmaxf(r[j].x - tau, 0.0f) * inv;
                o.y = fmaxf(r[j].y - tau, 0.0f) * inv;
                o.z = fmaxf(r[j].z - tau, 0.0f) * inv;
                o.w = fmaxf(r[j].w - tau, 0.0f) * inv;
                yr[idx] = o;
            }
        }
    }
}

extern "C" void kernel_launch(void* const* d_in, const int* in_sizes, int n_in,
                              void* d_out, int out_size, void* d_ws, size_t ws_size,
                              hipStream_t stream) {
    const float* X = (const float*)d_in[0];
    float*       Y = (float*)d_out;
    const int rows = in_sizes[0] / D;
    sparsemax_fused<<<rows, THREADS, 0, stream>>>(X, Y);
}